// Round 6
// baseline (219.702 us; speedup 1.0000x reference)
//
#include <hip/hip_runtime.h>
#include <hip/hip_bf16.h>

#define M 8192
#define N 8192
#define K 512
#define BM 128
#define BN 128
#define BK 64
#define EPSV 1e-8f

typedef __attribute__((ext_vector_type(8))) short bf16x8;
typedef __attribute__((ext_vector_type(4))) float f32x4;
typedef __attribute__((ext_vector_type(8))) unsigned short us8;

__device__ inline void gload_lds16(const void* g, void* l) {
  __builtin_amdgcn_global_load_lds(
      (const __attribute__((address_space(1))) unsigned int*)g,
      (__attribute__((address_space(3))) unsigned int*)l, 16, 0, 0);
}

// Pin memory-op issue order across this point (scheduler may not move
// loads/stores across an asm with a memory clobber).
#define MEMFENCE() asm volatile("" ::: "memory")

#define BARRIER()                          \
  do {                                     \
    asm volatile("" ::: "memory");         \
    __builtin_amdgcn_s_barrier();          \
    asm volatile("" ::: "memory");         \
  } while (0)

// Fused prep: cast f32 rows -> bf16, store INVERSE L2 norm (1/max(norm,1e-4)).
// Norms here are ~sqrt(512); inv1*inv2 == 1/max(w1*w2,1e-8) exactly.
__global__ __launch_bounds__(256) void prep_kernel(const float* __restrict__ img,
                                                   const float* __restrict__ txt,
                                                   unsigned short* __restrict__ Abf,
                                                   unsigned short* __restrict__ Bbf,
                                                   float* __restrict__ w1,
                                                   float* __restrict__ w2) {
  const int half = blockIdx.x >> 11;
  const int lb = blockIdx.x & 2047;
  const float* in = half ? txt : img;
  unsigned short* outb = half ? Bbf : Abf;
  float* norms = half ? w2 : w1;

  const int gw = (lb * 256 + threadIdx.x) >> 6;
  const int lane = threadIdx.x & 63;
  const float4* rp4 = (const float4*)(in + (size_t)gw * K);
  float4 v0 = rp4[lane * 2];
  float4 v1 = rp4[lane * 2 + 1];
  float ss = v0.x * v0.x + v0.y * v0.y + v0.z * v0.z + v0.w * v0.w +
             v1.x * v1.x + v1.y * v1.y + v1.z * v1.z + v1.w * v1.w;
  float f[8] = {v0.x, v0.y, v0.z, v0.w, v1.x, v1.y, v1.z, v1.w};
  us8 o;
#pragma unroll
  for (int i = 0; i < 8; ++i) {
    __hip_bfloat16 b = __float2bfloat16(f[i]);
    o[i] = *(unsigned short*)&b;
  }
  *(us8*)(outb + (size_t)gw * K + lane * 8) = o;
#pragma unroll
  for (int off = 32; off > 0; off >>= 1) ss += __shfl_down(ss, off, 64);
  if (lane == 0) norms[gw] = 1.0f / fmaxf(sqrtf(ss), 1e-4f);
}

// Persistent 128x128-tile GEMM, 512 blocks x 256 thr (2 blocks/CU), BK=64.
// Block: fixed row strip (bid>>3)*128; walks 8 col tiles ((bid&7)*8+t)*128.
// Tile t-1's epilogue stores are interleaved into tile t's K-loop.
// VMEM FIFO per step is FENCE-pinned to [loads x8][stores x8]; vmcnt(8)
// therefore guarantees all loads landed while stores stay in flight.
__global__ __launch_bounds__(256, 2) void gemm_kernel(const unsigned short* __restrict__ A,
                                                      const unsigned short* __restrict__ B,
                                                      const float* __restrict__ iw1,
                                                      const float* __restrict__ iw2,
                                                      float* __restrict__ C) {
  __shared__ __align__(128) unsigned short As[2][128 * 64];  // 2 x 16 KB
  __shared__ __align__(128) unsigned short Bs[2][128 * 64];  // 2 x 16 KB

  const int tid = threadIdx.x;
  const int wave = tid >> 6;
  const int lane = tid & 63;
  const int wr = wave >> 1;  // 0..1 : wave M-half (64 rows)
  const int wc = wave & 1;   // 0..1 : wave N-half (64 cols)
  const int fr = lane & 15;
  const int fq = lane >> 4;

  const int colBase = (int)(blockIdx.x & 7) * 8;  // 8 col-panels per XCD slot
  const int bRow = (int)(blockIdx.x >> 3) * BM;   // fixed row strip

  // staging: 8 rows x 128 B per wave per gload call; source col pre-swizzled
  // with involution byte^=((row&7)<<4); LDS dest linear (rule #21).
  const int srow = lane >> 3;                             // 0..7
  const int csw = ((lane & 7) * 16) ^ ((srow & 7) << 4);  // byte within 128B row

  auto stageA = [&](int buf, int kt) {
#pragma unroll
    for (int c = 0; c < 4; ++c)
      gload_lds16(A + (size_t)(bRow + c * 32 + wave * 8 + srow) * K + kt * BK + (csw >> 1),
                  (char*)&As[buf][0] + (c * 32 + wave * 8) * 128);
  };
  auto stageB = [&](int buf, int bCol, int kt) {
#pragma unroll
    for (int c = 0; c < 4; ++c)
      gload_lds16(B + (size_t)(bCol + c * 32 + wave * 8 + srow) * K + kt * BK + (csw >> 1),
                  (char*)&Bs[buf][0] + (c * 32 + wave * 8) * 128);
  };
  auto ldA = [&](int buf, int m, int kk) -> bf16x8 {
    const int r = wr * 64 + m * 16 + fr;
    return *(const bf16x8*)((const char*)&As[buf][0] + r * 128 +
                            ((kk * 64 + fq * 16) ^ ((r & 7) << 4)));
  };
  auto ldB = [&](int buf, int n, int kk) -> bf16x8 {
    const int r = wc * 64 + n * 16 + fr;
    return *(const bf16x8*)((const char*)&Bs[buf][0] + r * 128 +
                            ((kk * 64 + fq * 16) ^ ((r & 7) << 4)));
  };

  // inverse row norms for this lane's 16 output rows (fixed for block lifetime)
  float i1v[4][4];
#pragma unroll
  for (int m = 0; m < 4; ++m)
#pragma unroll
    for (int r = 0; r < 4; ++r) i1v[m][r] = iw1[bRow + wr * 64 + m * 16 + fq * 4 + r];

  f32x4 accA[4][4] = {}, accB[4][4] = {};
  float i2A[4] = {}, i2B[4] = {};

  auto colOf = [&](int t) { return (colBase + t) * BN; };

  // prologue: stage tile0 step0 into buf0
  stageA(0, 0);
  stageB(0, colOf(0), 0);
  asm volatile("s_waitcnt vmcnt(0)" ::: "memory");
  BARRIER();

  // One tile: accumulate `acc` (cols colCur), drain `prev` (cols colPrev).
  // Drain always issued; the p=0 fake-drain writes zeros to tile7's
  // addresses, overwritten later by the SAME lanes (program order wins).
  auto tile_body = [&](f32x4 (&acc)[4][4], float (&i2)[4],
                       f32x4 (&prev)[4][4], float (&i2p)[4],
                       int colCur, int colPrev, int colNext) {
#pragma unroll
    for (int n = 0; n < 4; ++n) i2[n] = iw2[colCur + wc * 64 + n * 16 + fr];
#pragma unroll
    for (int m = 0; m < 4; ++m)
#pragma unroll
      for (int n = 0; n < 4; ++n) acc[m][n] = (f32x4){0.f, 0.f, 0.f, 0.f};

#pragma unroll
    for (int s = 0; s < 8; ++s) {
      const int cur = s & 1, nxt = cur ^ 1;
      const int ktn = (s < 7) ? s + 1 : 0;
      const int colStage = (s < 7) ? colCur : colNext;

      // ---- phase 0: ds_read kk=0 frags ; stage A(next)
      bf16x8 a0[4], b0[4];
#pragma unroll
      for (int mm = 0; mm < 4; ++mm) a0[mm] = ldA(cur, mm, 0);
#pragma unroll
      for (int nn = 0; nn < 4; ++nn) b0[nn] = ldB(cur, nn, 0);
      stageA(nxt, ktn);
      BARRIER();
      __builtin_amdgcn_s_setprio(1);
#pragma unroll
      for (int mm = 0; mm < 4; ++mm)
#pragma unroll
        for (int nn = 0; nn < 4; ++nn)
          acc[mm][nn] = __builtin_amdgcn_mfma_f32_16x16x32_bf16(a0[mm], b0[nn],
                                                                acc[mm][nn], 0, 0, 0);
      __builtin_amdgcn_s_setprio(0);
      BARRIER();

      // ---- phase 1: ds_read kk=1 frags ; stage B(next) ; FENCE ; drain x8
      bf16x8 a1[4], b1[4];
#pragma unroll
      for (int mm = 0; mm < 4; ++mm) a1[mm] = ldA(cur, mm, 1);
#pragma unroll
      for (int nn = 0; nn < 4; ++nn) b1[nn] = ldB(cur, nn, 1);
      stageB(nxt, colStage, ktn);
      MEMFENCE();  // all 8 loads of this step precede the 8 stores in FIFO
      {
        const int dm = s >> 1, dn0 = (s & 1) * 2;
        const int row0 = bRow + wr * 64 + dm * 16 + fq * 4;
#pragma unroll
        for (int d = 0; d < 2; ++d) {
          const int dn = dn0 + d;
          const int col = colPrev + wc * 64 + dn * 16 + fr;
#pragma unroll
          for (int r = 0; r < 4; ++r)
            C[(size_t)(row0 + r) * N + col] = prev[dm][dn][r] * i1v[dm][r] * i2p[dn];
        }
      }
      BARRIER();
      __builtin_amdgcn_s_setprio(1);
#pragma unroll
      for (int mm = 0; mm < 4; ++mm)
#pragma unroll
        for (int nn = 0; nn < 4; ++nn)
          acc[mm][nn] = __builtin_amdgcn_mfma_f32_16x16x32_bf16(a1[mm], b1[nn],
                                                                acc[mm][nn], 0, 0, 0);
      __builtin_amdgcn_s_setprio(0);
      // FIFO: [st(s-1) x8][gA x4][gB x4][st(s) x8] -> vmcnt(8) completes all
      // loads, leaves this step's store group in flight.
      asm volatile("s_waitcnt vmcnt(8)" ::: "memory");
      BARRIER();
    }
  };

  // 8 tiles as 4 pairs; accA/accB alternate (static names, rule #20).
#pragma clang loop unroll(disable)
  for (int p = 0; p < 4; ++p) {
    const int tE = 2 * p, tO = 2 * p + 1;
    tile_body(accA, i2A, accB, i2B, colOf(tE), p ? colOf(tE - 1) : colOf(7), colOf(tO));
    tile_body(accB, i2B, accA, i2A, colOf(tO), colOf(tE), (p < 3) ? colOf(tO + 1) : colOf(0));
  }

  // tail: drain tile 7 (accB) — overwrites the fake-drain zeros.
#pragma unroll
  for (int dm = 0; dm < 4; ++dm) {
    const int row0 = bRow + wr * 64 + dm * 16 + fq * 4;
#pragma unroll
    for (int dn = 0; dn < 4; ++dn) {
      const int col = colOf(7) + wc * 64 + dn * 16 + fr;
#pragma unroll
      for (int r = 0; r < 4; ++r)
        C[(size_t)(row0 + r) * N + col] = accB[dm][dn][r] * i1v[dm][r] * i2B[dn];
    }
  }
}

extern "C" void kernel_launch(void* const* d_in, const int* in_sizes, int n_in,
                              void* d_out, int out_size, void* d_ws, size_t ws_size,
                              hipStream_t stream) {
  (void)in_sizes; (void)n_in; (void)out_size; (void)ws_size;
  const float* img = (const float*)d_in[0];
  const float* txt = (const float*)d_in[1];
  float* out = (float*)d_out;

  unsigned short* Abf = (unsigned short*)d_ws;
  unsigned short* Bbf = Abf + (size_t)M * K;
  float* w1 = (float*)(Bbf + (size_t)N * K);
  float* w2 = w1 + M;

  prep_kernel<<<4096, 256, 0, stream>>>(img, txt, Abf, Bbf, w1, w2);
  gemm_kernel<<<512, 256, 0, stream>>>(Abf, Bbf, w1, w2, out);
}

// Round 7
// 109.163 us; speedup vs baseline: 2.0126x; 2.0126x over previous
//
#include <hip/hip_runtime.h>
#include <hip/hip_bf16.h>

#define M 8192
#define N 8192
#define K 512
#define BM 256
#define BN 128
#define BK 32
#define NT (K / BK)  // 16 K-steps
#define EPSV 1e-8f

typedef __attribute__((ext_vector_type(8))) short bf16x8;
typedef __attribute__((ext_vector_type(4))) float f32x4;
typedef __attribute__((ext_vector_type(8))) unsigned short us8;

__device__ inline void gload_lds16(const void* g, void* l) {
  __builtin_amdgcn_global_load_lds(
      (const __attribute__((address_space(1))) unsigned int*)g,
      (__attribute__((address_space(3))) unsigned int*)l, 16, 0, 0);
}

#define BARRIER()                          \
  do {                                     \
    asm volatile("" ::: "memory");         \
    __builtin_amdgcn_s_barrier();          \
    asm volatile("" ::: "memory");         \
  } while (0)

// Fused prep: cast f32 rows -> bf16, store INVERSE L2 norm (1/max(norm,1e-4)).
// Norms are ~sqrt(512) here, so inv1*inv2 == 1/max(w1*w2,1e-8) exactly.
__global__ __launch_bounds__(256) void prep_kernel(const float* __restrict__ img,
                                                   const float* __restrict__ txt,
                                                   unsigned short* __restrict__ Abf,
                                                   unsigned short* __restrict__ Bbf,
                                                   float* __restrict__ w1,
                                                   float* __restrict__ w2) {
  const int half = blockIdx.x >> 11;
  const int lb = blockIdx.x & 2047;
  const float* in = half ? txt : img;
  unsigned short* outb = half ? Bbf : Abf;
  float* norms = half ? w2 : w1;

  const int gw = (lb * 256 + threadIdx.x) >> 6;
  const int lane = threadIdx.x & 63;
  const float4* rp4 = (const float4*)(in + (size_t)gw * K);
  float4 v0 = rp4[lane * 2];
  float4 v1 = rp4[lane * 2 + 1];
  float ss = v0.x * v0.x + v0.y * v0.y + v0.z * v0.z + v0.w * v0.w +
             v1.x * v1.x + v1.y * v1.y + v1.z * v1.z + v1.w * v1.w;
  float f[8] = {v0.x, v0.y, v0.z, v0.w, v1.x, v1.y, v1.z, v1.w};
  us8 o;
#pragma unroll
  for (int i = 0; i < 8; ++i) {
    __hip_bfloat16 b = __float2bfloat16(f[i]);
    o[i] = *(unsigned short*)&b;
  }
  *(us8*)(outb + (size_t)gw * K + lane * 8) = o;
#pragma unroll
  for (int off = 32; off > 0; off >>= 1) ss += __shfl_down(ss, off, 64);
  if (lane == 0) norms[gw] = 1.0f / fmaxf(sqrtf(ss), 1e-4f);
}

// 256x128 bf16 GEMM, BK=32, 8 waves (wave tile 64x64), 2 blocks/CU.
// ONE phase + ONE barrier per K-step: {stage A(t+1) + B(t+2); ds_read 8
// frags; 16 MFMA; vmcnt(1); barrier}. Legal: ds_reads of buf[cur] complete
// (lgkmcnt before MFMA) before every wave's end-of-step barrier, so next
// step's staging cannot overwrite live data.
// LDS rows are 64B (BK=32): a wave's fragment read covers 64 distinct
// contiguous 16B chunks -> conflict-free, no swizzle, linear gload_lds dest.
__global__ __launch_bounds__(512, 4) void gemm_kernel(const unsigned short* __restrict__ A,
                                                      const unsigned short* __restrict__ B,
                                                      const float* __restrict__ iw1,
                                                      const float* __restrict__ iw2,
                                                      float* __restrict__ C) {
  __shared__ __align__(128) unsigned short As[2][BM * BK];  // 2 x 16 KB
  __shared__ __align__(128) unsigned short Bs[3][BN * BK];  // 3 x 8 KB

  const int tid = threadIdx.x;
  const int wave = tid >> 6;
  const int lane = tid & 63;
  const int wr = wave >> 1;  // 0..3 : M strip of 64
  const int wc = wave & 1;   // 0..1 : N strip of 64
  const int fr = lane & 15;
  const int fq = lane >> 4;

  // Two-level swizzle: xcd = bid&7 owns col-panels [xcd*8, xcd*8+8) -> its
  // 1 MB B working set stays L2-resident for the whole kernel; idx walks
  // (row panel, col panel) row-major so concurrent A panels (~2MB) L2-fit.
  const int xcd = blockIdx.x & 7;
  const int idx = blockIdx.x >> 3;              // 0..255
  const int bRow = (idx >> 3) * BM;             // 32 row-panels of 256
  const int bCol = (xcd * 8 + (idx & 7)) * BN;  // 64 col-panels of 128

  const int srow = lane >> 2;       // 0..15 row within a 16-row slab
  const int scol = (lane & 3) * 8;  // bf16 col offset (16B granules)

  auto stageA = [&](int buf, int kt) {
#pragma unroll
    for (int c = 0; c < 2; ++c)
      gload_lds16(A + (size_t)(bRow + c * 128 + wave * 16 + srow) * K + kt * BK + scol,
                  (char*)&As[buf][0] + (c * 128 + wave * 16) * 64);
  };
  auto stageB = [&](int buf, int kt) {
    gload_lds16(B + (size_t)(bCol + wave * 16 + srow) * K + kt * BK + scol,
                (char*)&Bs[buf][0] + wave * 16 * 64);
  };
  auto ldA = [&](int buf, int r) -> bf16x8 {
    return *(const bf16x8*)((const char*)&As[buf][0] + r * 64 + fq * 16);
  };
  auto ldB = [&](int buf, int r) -> bf16x8 {
    return *(const bf16x8*)((const char*)&Bs[buf][0] + r * 64 + fq * 16);
  };

  f32x4 acc[4][4] = {};

  // Prologue: A(0) [2 loads], B(0) [1], B(1) [1]; need A0,B0 landed.
  stageA(0, 0);
  stageB(0, 0);
  stageB(1, 1);
  asm volatile("s_waitcnt vmcnt(1)" ::: "memory");
  BARRIER();

#pragma unroll
  for (int t = 0; t < NT; ++t) {
    const int cur = t & 1, nxt = cur ^ 1;
    const int bc = t % 3, b2 = (t + 2) % 3;

    if (t + 1 < NT) stageA(nxt, t + 1);  // 2 gloads
    if (t + 2 < NT) stageB(b2, t + 2);   // 1 gload

    bf16x8 a[4], b[4];
#pragma unroll
    for (int m = 0; m < 4; ++m) a[m] = ldA(cur, wr * 64 + m * 16 + fr);
#pragma unroll
    for (int n = 0; n < 4; ++n) b[n] = ldB(bc, wc * 64 + n * 16 + fr);

    __builtin_amdgcn_s_setprio(1);
#pragma unroll
    for (int m = 0; m < 4; ++m)
#pragma unroll
      for (int n = 0; n < 4; ++n)
        acc[m][n] = __builtin_amdgcn_mfma_f32_16x16x32_bf16(a[m], b[n], acc[m][n], 0, 0, 0);
    __builtin_amdgcn_s_setprio(0);

    if (t < NT - 2) {
      // FIFO at wait: [B(t+1)][A(t+1)x2][B(t+2)] -> vmcnt(1) lands everything
      // step t+1 needs, leaves only B(t+2) in flight.
      asm volatile("s_waitcnt vmcnt(1)" ::: "memory");
    } else if (t == NT - 2) {
      asm volatile("s_waitcnt vmcnt(0)" ::: "memory");
    }
    BARRIER();
  }

  // Epilogue (norm scales loaded here to keep K-loop VGPR <= 128).
  // C/D layout: col = lane&15, row = (lane>>4)*4 + reg.
  float i1v[4][4], i2v[4];
#pragma unroll
  for (int m = 0; m < 4; ++m)
#pragma unroll
    for (int r = 0; r < 4; ++r) i1v[m][r] = iw1[bRow + wr * 64 + m * 16 + fq * 4 + r];
#pragma unroll
  for (int n = 0; n < 4; ++n) i2v[n] = iw2[bCol + wc * 64 + n * 16 + fr];

#pragma unroll
  for (int m = 0; m < 4; ++m) {
    const int row0 = bRow + wr * 64 + m * 16 + fq * 4;
#pragma unroll
    for (int n = 0; n < 4; ++n) {
      const int col = bCol + wc * 64 + n * 16 + fr;
      f32x4 v = acc[m][n];
#pragma unroll
      for (int r = 0; r < 4; ++r)
        C[(size_t)(row0 + r) * N + col] = v[r] * i1v[m][r] * i2v[n];
    }
  }
}

extern "C" void kernel_launch(void* const* d_in, const int* in_sizes, int n_in,
                              void* d_out, int out_size, void* d_ws, size_t ws_size,
                              hipStream_t stream) {
  (void)in_sizes; (void)n_in; (void)out_size; (void)ws_size;
  const float* img = (const float*)d_in[0];
  const float* txt = (const float*)d_in[1];
  float* out = (float*)d_out;

  unsigned short* Abf = (unsigned short*)d_ws;
  unsigned short* Bbf = Abf + (size_t)M * K;
  float* w1 = (float*)(Bbf + (size_t)N * K);
  float* w2 = w1 + M;

  prep_kernel<<<4096, 256, 0, stream>>>(img, txt, Abf, Bbf, w1, w2);
  gemm_kernel<<<(M / BM) * (N / BN), 512, 0, stream>>>(Abf, Bbf, w1, w2, out);
}